// Round 10
// baseline (774.036 us; speedup 1.0000x reference)
//
#include <hip/hip_runtime.h>
#include <hip/hip_cooperative_groups.h>
#include <math.h>

namespace cg = cooperative_groups;

#define Bb 16
#define Cc 512
#define Gg 8
#define Nn 7680               // 48*160
#define NCH 64                // chunks per batch
#define POSCH (Nn / NCH)      // 120 positions per chunk
#define LN_EPS 1e-3f

typedef float v4f __attribute__((ext_vector_type(4)));

__device__ __forceinline__ float wave_sum(float v) {
#pragma unroll
    for (int o = 32; o > 0; o >>= 1) v += __shfl_xor(v, o);
    return v;
}
__device__ __forceinline__ float wave_max(float v) {
#pragma unroll
    for (int o = 32; o > 0; o >>= 1) v = fmaxf(v, __shfl_xor(v, o));
    return v;
}

// ONE cooperative kernel, grid = (NCH, Bb) x 256 threads (4096 waves, fits
// 256 CUs x 32 waves co-resident).
// Phase 1: fused logits + online-softmax pooling (identical math to the
//          benched k_pool) -> pctx/pms in ws.
// Phase 2: 16 blocks (chunk==0) do combine + w1 -> LN -> ReLU -> w2 -> tvec.
// Phase 3: every block re-reads ITS OWN 240 KB x-slice (hot in L2/L3) and
//          nt-stores out = x + tvec[b].
__global__ __launch_bounds__(256) void k_fused(
    const float* __restrict__ x, const float* __restrict__ w_mask,
    const float* __restrict__ b_mask, const float* __restrict__ w1,
    const float* __restrict__ b1, const float* __restrict__ gamma,
    const float* __restrict__ beta, const float* __restrict__ w2,
    const float* __restrict__ b2, float* __restrict__ pctx,
    float* __restrict__ pms, float* __restrict__ tvec,
    float* __restrict__ out)
{
    cg::grid_group grid = cg::this_grid();
    const int chunk = blockIdx.x;
    const int b = blockIdx.y;
    const int t = threadIdx.x;
    const int w = t >> 6;
    const int lane = t & 63;
    const int g = lane >> 3;

    __shared__ float lm[4][8], lsv[4][8];
    __shared__ float lacc[4][Cc];
    __shared__ float escale[Gg][NCH];
    __shared__ float SgS[Gg];
    __shared__ float cs[Cc];
    __shared__ float hs[Cc];
    __shared__ float red[4];
    __shared__ float tl[Cc];

    // ---------------- phase 1: pool ----------------
    {
        int cw = (lane & 7) * 8;
        float4 m0 = *(const float4*)(w_mask + cw);
        float4 m1 = *(const float4*)(w_mask + cw + 4);
        float bm = b_mask[0];

        float mrun = -1e30f, srun = 0.f;
        float acc[8];
#pragma unroll
        for (int j = 0; j < 8; ++j) acc[j] = 0.f;

        const float* xbase = x + ((size_t)b * Nn + (size_t)chunk * POSCH) * Cc + lane * 8;
        for (int p = w; p < POSCH; p += 4) {
            const float* xp = xbase + (size_t)p * Cc;
            float4 a0 = *(const float4*)(xp);
            float4 a1 = *(const float4*)(xp + 4);
            float v[8] = {a0.x, a0.y, a0.z, a0.w, a1.x, a1.y, a1.z, a1.w};
            float d = a0.x * m0.x + a0.y * m0.y + a0.z * m0.z + a0.w * m0.w
                    + a1.x * m1.x + a1.y * m1.y + a1.z * m1.z + a1.w * m1.w;
            d += __shfl_xor(d, 1);
            d += __shfl_xor(d, 2);
            d += __shfl_xor(d, 4);
            float l = (d + bm) * 0.125f;
            float mnew = fmaxf(mrun, l);
            float scale = __expf(mrun - mnew);
            float e = __expf(l - mnew);
            srun = srun * scale + e;
#pragma unroll
            for (int j = 0; j < 8; ++j) acc[j] = acc[j] * scale + e * v[j];
            mrun = mnew;
        }

        if ((lane & 7) == 0) { lm[w][g] = mrun; lsv[w][g] = srun; }
        __syncthreads();
        float M = fmaxf(fmaxf(lm[0][g], lm[1][g]), fmaxf(lm[2][g], lm[3][g]));
        float wscale = __expf(mrun - M);
#pragma unroll
        for (int j = 0; j < 8; ++j) lacc[w][lane * 8 + j] = acc[j] * wscale;
        __syncthreads();
        for (int c = t; c < Cc; c += 256) {
            float s4 = lacc[0][c] + lacc[1][c] + lacc[2][c] + lacc[3][c];
            pctx[((size_t)b * NCH + chunk) * Cc + c] = s4;
        }
        if (t < 8) {
            int gg = t;
            float Mg = fmaxf(fmaxf(lm[0][gg], lm[1][gg]), fmaxf(lm[2][gg], lm[3][gg]));
            float Sg = lsv[0][gg] * __expf(lm[0][gg] - Mg) + lsv[1][gg] * __expf(lm[1][gg] - Mg)
                     + lsv[2][gg] * __expf(lm[2][gg] - Mg) + lsv[3][gg] * __expf(lm[3][gg] - Mg);
            pms[(((size_t)b * Gg + gg) * NCH + chunk) * 2 + 0] = Mg;
            pms[(((size_t)b * Gg + gg) * NCH + chunk) * 2 + 1] = Sg;
        }
    }

    grid.sync();

    // ---------------- phase 2: MLP (blocks with chunk==0; one per b) -------
    if (chunk == 0) {
        // escale + Sg: wave w handles headers 2w and 2w+1; lane = chunk idx
        for (int gi = 2 * w; gi <= 2 * w + 1; ++gi) {
            float2 msv = *(const float2*)(pms + (((size_t)b * Gg + gi) * NCH + lane) * 2);
            float M = wave_max(msv.x);
            float e = __expf(msv.x - M);
            escale[gi][lane] = e;
            float S = wave_sum(msv.y * e);
            if (lane == 0) SgS[gi] = S;
        }
        __syncthreads();
        // combine partial ctx: thread t owns channels t and t+256
        {
            int g0 = t >> 6, g1 = (t + 256) >> 6;
            float a0 = 0.f, a1 = 0.f;
#pragma unroll 4
            for (int ch = 0; ch < NCH; ++ch) {
                const float* p = pctx + ((size_t)b * NCH + ch) * Cc;
                a0 += p[t] * escale[g0][ch];
                a1 += p[t + 256] * escale[g1][ch];
            }
            cs[t] = a0 / SgS[g0];
            cs[t + 256] = a1 / SgS[g1];
        }
        __syncthreads();

        // h = ctx @ w1 + b1  (2 output channels per thread)
        float h0 = b1[t], h1 = b1[t + 256];
#pragma unroll 8
        for (int k = 0; k < Cc; ++k) {
            float c = cs[k];
            const float* r = w1 + (size_t)k * Cc;
            h0 = fmaf(c, r[t], h0);
            h1 = fmaf(c, r[t + 256], h1);
        }

        // LayerNorm over 512 (2 values/thread, 4 waves)
        float s = wave_sum(h0 + h1);
        if (lane == 0) red[w] = s;
        __syncthreads();
        float mu = (red[0] + red[1] + red[2] + red[3]) * (1.0f / Cc);
        __syncthreads();
        float d0 = h0 - mu, d1 = h1 - mu;
        float sq = wave_sum(d0 * d0 + d1 * d1);
        if (lane == 0) red[w] = sq;
        __syncthreads();
        float var = (red[0] + red[1] + red[2] + red[3]) * (1.0f / Cc);
        float rs = rsqrtf(var + LN_EPS);
        hs[t]       = fmaxf(d0 * rs * gamma[t] + beta[t], 0.f);
        hs[t + 256] = fmaxf(d1 * rs * gamma[t + 256] + beta[t + 256], 0.f);
        __syncthreads();

        // t = relu(hn) @ w2 + b2
        float tv0 = b2[t], tv1 = b2[t + 256];
#pragma unroll 8
        for (int k = 0; k < Cc; ++k) {
            float hh = hs[k];
            const float* r = w2 + (size_t)k * Cc;
            tv0 = fmaf(hh, r[t], tv0);
            tv1 = fmaf(hh, r[t + 256], tv1);
        }
        tvec[(size_t)b * Cc + t] = tv0;
        tvec[(size_t)b * Cc + t + 256] = tv1;
    }

    grid.sync();

    // ---------------- phase 3: residual on own x-slice ----------------
    tl[t] = tvec[(size_t)b * Cc + t];
    tl[t + 256] = tvec[(size_t)b * Cc + t + 256];
    __syncthreads();
    {
        const size_t base = ((size_t)b * Nn + (size_t)chunk * POSCH) * Cc;
        const v4f* x4 = (const v4f*)(x + base);
        v4f* o4 = (v4f*)(out + base);
        const int total4 = POSCH * (Cc / 4);  // 15360
        for (int i = t; i < total4; i += 256) {
            int c4 = i & 127;
            v4f xv = x4[i];
            v4f tv = *(const v4f*)(&tl[c4 * 4]);
            v4f ov = xv + tv;
            __builtin_nontemporal_store(ov, &o4[i]);
        }
    }
}

extern "C" void kernel_launch(void* const* d_in, const int* in_sizes, int n_in,
                              void* d_out, int out_size, void* d_ws, size_t ws_size,
                              hipStream_t stream) {
    const float* x      = (const float*)d_in[0];
    const float* w_mask = (const float*)d_in[1];
    const float* b_mask = (const float*)d_in[2];
    const float* w1     = (const float*)d_in[3];
    const float* b1     = (const float*)d_in[4];
    const float* gamma  = (const float*)d_in[5];
    const float* beta   = (const float*)d_in[6];
    const float* w2     = (const float*)d_in[7];
    const float* b2     = (const float*)d_in[8];
    float* out = (float*)d_out;

    float* ws   = (float*)d_ws;
    float* pctx = ws;                                   // B*NCH*C = 524288 floats
    float* pms  = pctx + (size_t)Bb * NCH * Cc;         // B*G*NCH*2 = 16384
    float* tvec = pms + (size_t)Bb * Gg * NCH * 2;      // B*C = 8192

    void* args[] = { (void*)&x, (void*)&w_mask, (void*)&b_mask, (void*)&w1,
                     (void*)&b1, (void*)&gamma, (void*)&beta, (void*)&w2,
                     (void*)&b2, (void*)&pctx, (void*)&pms, (void*)&tvec,
                     (void*)&out };
    hipLaunchCooperativeKernel((const void*)k_fused, dim3(NCH, Bb),
                               dim3(256, 1, 1), args, 0, stream);
}